// Round 6
// baseline (3801.554 us; speedup 1.0000x reference)
//
#include <hip/hip_runtime.h>
#include <math.h>

// Persistent fp16-MFMA LSTM, round 9. T=512, B=64, IN=512, H=1024, K=1536.
// 256 blocks x 256 threads (1 block/CU). Changes vs round 8:
//  - TAGGED h: hbuf cell = u32 ((fp16 h)<<16 | step_tag). Producers store
//    tagged h with NO drain (raw s_barrier before the flag store instead of
//    __syncthreads/vmcnt(0)). Flags are advisory; consumers tag-check every
//    staged 16B granule (4 tags) and retry stale granules. Data dependency
//    (producer must stage tag t+1 from ALL group members before writing
//    t+2) makes the 2-buffer scheme race-free without any strong barrier.
//  - speculative A-half first pass issued in the wait window (after xpart,
//    before the flag poll): fresh granules land in LDS under the wait;
//    stale ones retried at loop top. B-half loads overlap MFMA-A (as r8).
//  - removes from the critical path: the producer drain RTT (~1 IF RTT) and
//    part of the staging RTT.
//  - unchanged: 2-D tile (4 batch-groups x 64 j-groups), all-scan group
//    flags, out-stores + xpart(t+1) in the wait window, packed h gather,
//    fast sigmoid/tanh.
// ws grows 256 KB (hbuf u32). Fallback (!PRE) keeps the full drain and is
// correct if ws no longer fits PRE.

namespace {

constexpr int T_STEPS = 512;
constexpr int B = 64;
constexpr int IN = 512;
constexpr int H = 1024;
constexpr int K = IN + H;    // 1536
constexpr int NBLK = 256;
constexpr int NXMF = IN / 32;  // 16 x-part MFMAs
constexpr int NHMF = H / 32;   // 32 h-part MFMAs
constexpr int WPITCH = K + 8;  // one-time W staging pitch (halves)
constexpr int HPITCH = H + 8;  // per-step h staging pitch (halves)

// ws layout (bytes)
constexpr size_t HBUF_OFF = 0;                               // 2*B*H u32
constexpr size_t XBUF_OFF = HBUF_OFF + 2ull * B * H * 4;     // 2*B*IN fp16
constexpr size_t BAR_OFF = XBUF_OFF + 2ull * B * IN * 2;     // 1056 uints
constexpr size_t COMBX_OFF = BAR_OFF + 1056ull * 4;          // T*B*IN fp16
constexpr size_t NEED_PRE = COMBX_OFF + (size_t)T_STEPS * B * IN * 2;

typedef __attribute__((ext_vector_type(8))) _Float16 f16x8;
typedef __attribute__((ext_vector_type(4))) float f32x4;

__device__ __forceinline__ f16x8 load_sc1_16B(const _Float16* p) {
  union {
    unsigned long long u[2];
    f16x8 v;
  } cv;
  const unsigned long long* q = (const unsigned long long*)p;
  cv.u[0] = __hip_atomic_load(q, __ATOMIC_RELAXED, __HIP_MEMORY_SCOPE_AGENT);
  cv.u[1] =
      __hip_atomic_load(q + 1, __ATOMIC_RELAXED, __HIP_MEMORY_SCOPE_AGENT);
  return cv.v;
}

__device__ __forceinline__ void store_sc1_u64p(unsigned long long* p,
                                               unsigned long long v) {
  __hip_atomic_store(p, v, __ATOMIC_RELAXED, __HIP_MEMORY_SCOPE_AGENT);
}

__device__ __forceinline__ void store_sc1_u32(unsigned* p, unsigned v) {
  __hip_atomic_store(p, v, __ATOMIC_RELAXED, __HIP_MEMORY_SCOPE_AGENT);
}

// |err| ~1e-7 relative — far below the fp16 h quantization already present.
__device__ __forceinline__ float fast_sigmoid(float z) {
  return __builtin_amdgcn_rcpf(1.0f + __expf(-z));
}
__device__ __forceinline__ float fast_tanh(float z) {
  return 1.0f - 2.0f * __builtin_amdgcn_rcpf(1.0f + __expf(2.0f * z));
}

// Prefilled-mode prep: combx[t][b][k] = fp16(x), zero hbuf(u32), zero bar.
__global__ void prep_pre(const float* __restrict__ x,
                         _Float16* __restrict__ combx,
                         unsigned* __restrict__ hbuf,
                         unsigned* __restrict__ bar) {
  const size_t i = (size_t)blockIdx.x * 256 + threadIdx.x;
  if (i < (size_t)T_STEPS * B * IN) combx[i] = (_Float16)x[i];
  if (i < 2ull * B * H) hbuf[i] = 0u;  // h=0, tag=0
  if (i < 1056) bar[i] = 0u;
}

// Fallback prep: xbuf[0] = fp16(x[0]), zero hbuf(u32), zero bar.
__global__ void prep_fb(const float* __restrict__ x,
                        _Float16* __restrict__ xbuf,
                        unsigned* __restrict__ hbuf,
                        unsigned* __restrict__ bar) {
  const size_t i = (size_t)blockIdx.x * 256 + threadIdx.x;
  if (i < (size_t)B * IN) xbuf[i] = (_Float16)x[i];
  if (i < 2ull * B * H) hbuf[i] = 0u;
  if (i < 1056) bar[i] = 0u;
}

template <bool PRE>
__global__ __launch_bounds__(256, 1) void lstm_persist(
    const float* __restrict__ x, const float* __restrict__ Wf,
    const float* __restrict__ Wi, const float* __restrict__ Wg,
    const float* __restrict__ Wo, const float* __restrict__ bf,
    const float* __restrict__ bi_, const float* __restrict__ bg,
    const float* __restrict__ bo, float* __restrict__ out,
    _Float16* __restrict__ combx, _Float16* __restrict__ xbuf,
    unsigned* __restrict__ hbuf, unsigned* __restrict__ bar) {
  __shared__ _Float16 Wlds[16 * WPITCH];  // one-time W staging
  __shared__ _Float16 Hlds[16 * HPITCH];  // per-step h staging (33 KB)

  const int blk = blockIdx.x;
  const int tid = threadIdx.x;
  const int bgrp = blk & 3;    // batch group: rows [16*bgrp, 16*bgrp+16)
  const int jgrp = blk >> 2;   // j group: cols [16*jgrp, 16*jgrp+16)
  const int jbase = jgrp * 16;

  const int lane = tid & 63;
  const int wv = tid >> 6;
  const int q = lane >> 4;
  const int n = lane & 15;
  const int gate = n >> 2;
  const int jj = n & 3;
  const int j0w = jbase + wv * 4;  // this wave's 4 output cols
  const int brow0 = bgrp * 16;     // first batch row of this block

  // ---- one-time: stage W in 4 chunks (4 cols x 4 gates each), lift ----
  f16x8 Bfrag[NXMF + NHMF];  // 48 frags, resident all steps
  {
    const float* wptr[4] = {Wf, Wi, Wg, Wo};
    for (int c = 0; c < 4; ++c) {
#pragma unroll
      for (int g = 0; g < 4; ++g) {
        const float* wsrc = wptr[g];
        for (int it = 0; it < K / 256; ++it) {
          const int k = it * 256 + tid;
          const float4 w =
              *(const float4*)(wsrc + (size_t)k * H + jbase + c * 4);
          Wlds[(g * 4 + 0) * WPITCH + k] = (_Float16)w.x;
          Wlds[(g * 4 + 1) * WPITCH + k] = (_Float16)w.y;
          Wlds[(g * 4 + 2) * WPITCH + k] = (_Float16)w.z;
          Wlds[(g * 4 + 3) * WPITCH + k] = (_Float16)w.w;
        }
      }
      __syncthreads();
      if (wv == c) {
#pragma unroll
        for (int kk = 0; kk < NXMF + NHMF; ++kk) {
          Bfrag[kk] = *(const f16x8*)(&Wlds[n * WPITCH + kk * 32 + q * 8]);
        }
      }
      __syncthreads();
    }
  }

  const float* bptr[4] = {bf, bi_, bg, bo};
  const float bias_v = bptr[gate][j0w + jj];

  float c_reg[4] = {0.f, 0.f, 0.f, 0.f};

  // all-scan barrier state: 64 u32 flags per group (4 cache lines)
  unsigned* flags = bar + bgrp * 64;

  // ---- tagged staging helpers (A half: cols [0,512), B: [512,1024)) ----
  // granule i of this thread: g2 = tid + i*256; row = g2>>7; colgrp = g2&127.
  auto issue_half = [&](const unsigned* hb32, int halfBase, uint4* v,
                        unsigned pend) {
#pragma unroll
    for (int i = 0; i < 8; ++i)
      if (pend & (1u << i)) {
        const int g2 = tid + i * 256;
        const int row = g2 >> 7;
        const int cg = g2 & 127;
        const unsigned* p = hb32 + (size_t)row * H + halfBase + cg * 4;
        const unsigned long long u0 = __hip_atomic_load(
            (const unsigned long long*)p, __ATOMIC_RELAXED,
            __HIP_MEMORY_SCOPE_AGENT);
        const unsigned long long u1 = __hip_atomic_load(
            (const unsigned long long*)p + 1, __ATOMIC_RELAXED,
            __HIP_MEMORY_SCOPE_AGENT);
        v[i].x = (unsigned)u0;
        v[i].y = (unsigned)(u0 >> 32);
        v[i].z = (unsigned)u1;
        v[i].w = (unsigned)(u1 >> 32);
      }
  };
  auto check_half = [&](int halfBase, uint4* v, unsigned tag,
                        unsigned& pend) {
#pragma unroll
    for (int i = 0; i < 8; ++i)
      if (pend & (1u << i)) {
        const uint4 t4 = v[i];
        const bool ok =
            ((t4.x & 0xFFFFu) == tag) & ((t4.y & 0xFFFFu) == tag) &
            ((t4.z & 0xFFFFu) == tag) & ((t4.w & 0xFFFFu) == tag);
        if (ok) {
          const int g2 = tid + i * 256;
          const int row = g2 >> 7;
          const int cg = g2 & 127;
          const unsigned lo = (t4.x >> 16) | (t4.y & 0xFFFF0000u);
          const unsigned hi = (t4.z >> 16) | (t4.w & 0xFFFF0000u);
          *(unsigned long long*)(&Hlds[row * HPITCH + halfBase + cg * 4]) =
              (unsigned long long)lo | ((unsigned long long)hi << 32);
          pend &= ~(1u << i);
        }
      }
  };

  // x-part GEMM for step t -> acc_x (bias + x contribution).
  f32x4 acc_x;
  auto xpart = [&](int t) {
    f32x4 a = {bias_v, bias_v, bias_v, bias_v};
    f32x4 b = {0.f, 0.f, 0.f, 0.f};
    if constexpr (PRE) {
      const _Float16* ab =
          combx + (size_t)t * B * IN + (size_t)(brow0 + n) * IN + q * 8;
#pragma unroll
      for (int kk = 0; kk < NXMF; kk += 2) {
        f16x8 f0 = *(const f16x8*)(ab + kk * 32);
        f16x8 f1 = *(const f16x8*)(ab + (kk + 1) * 32);
        a = __builtin_amdgcn_mfma_f32_16x16x32_f16(f0, Bfrag[kk], a, 0, 0, 0);
        b = __builtin_amdgcn_mfma_f32_16x16x32_f16(f1, Bfrag[kk + 1], b, 0, 0,
                                                   0);
      }
    } else {
      const _Float16* ab =
          xbuf + (size_t)(t & 1) * B * IN + (size_t)(brow0 + n) * IN + q * 8;
#pragma unroll
      for (int kk = 0; kk < NXMF; kk += 2) {
        f16x8 f0 = load_sc1_16B(ab + kk * 32);
        f16x8 f1 = load_sc1_16B(ab + (kk + 1) * 32);
        a = __builtin_amdgcn_mfma_f32_16x16x32_f16(f0, Bfrag[kk], a, 0, 0, 0);
        b = __builtin_amdgcn_mfma_f32_16x16x32_f16(f1, Bfrag[kk + 1], b, 0, 0,
                                                   0);
      }
    }
    acc_x = a + b;
  };

  xpart(0);

  // prologue: first-pass A staging for t=0 (buffer 0, tag 0: passes now)
  uint4 vA[8];
  unsigned pendA = 0xFFu;
  {
    const unsigned* hb32 = hbuf + (size_t)brow0 * H;
    issue_half(hb32, 0, vA, pendA);
    check_half(0, vA, 0u, pendA);
  }

  for (int t = 0; t < T_STEPS; ++t) {
    const unsigned tagt = (unsigned)t;
    const unsigned* hb32 =
        hbuf + (size_t)(t & 1) * B * H + (size_t)brow0 * H;

    // ---- finish A staging (retry stale granules) ----
    while (pendA) {
      issue_half(hb32, 0, vA, pendA);
      check_half(0, vA, tagt, pendA);
      if (pendA) __builtin_amdgcn_s_sleep(1);
    }
    __syncthreads();

    // ---- B first pass issued; loads fly during MFMA A ----
    uint4 vB[8];
    unsigned pendB = 0xFFu;
    issue_half(hb32, 512, vB, pendB);

    // ---- h part A: kk 0..15 ----
    f32x4 a0 = acc_x;
    f32x4 a1 = {0.f, 0.f, 0.f, 0.f};
    f32x4 a2 = {0.f, 0.f, 0.f, 0.f};
    f32x4 a3 = {0.f, 0.f, 0.f, 0.f};
    {
      const _Float16* hl = &Hlds[n * HPITCH + q * 8];
#pragma unroll
      for (int kk = 0; kk < NHMF / 2; kk += 4) {
        f16x8 f0 = *(const f16x8*)(hl + kk * 32);
        f16x8 f1 = *(const f16x8*)(hl + (kk + 1) * 32);
        f16x8 f2 = *(const f16x8*)(hl + (kk + 2) * 32);
        f16x8 f3 = *(const f16x8*)(hl + (kk + 3) * 32);
        a0 = __builtin_amdgcn_mfma_f32_16x16x32_f16(f0, Bfrag[NXMF + kk], a0,
                                                    0, 0, 0);
        a1 = __builtin_amdgcn_mfma_f32_16x16x32_f16(f1, Bfrag[NXMF + kk + 1],
                                                    a1, 0, 0, 0);
        a2 = __builtin_amdgcn_mfma_f32_16x16x32_f16(f2, Bfrag[NXMF + kk + 2],
                                                    a2, 0, 0, 0);
        a3 = __builtin_amdgcn_mfma_f32_16x16x32_f16(f3, Bfrag[NXMF + kk + 3],
                                                    a3, 0, 0, 0);
      }
    }

    // ---- B: check, retry stragglers, publish to LDS ----
    check_half(512, vB, tagt, pendB);
    while (pendB) {
      issue_half(hb32, 512, vB, pendB);
      check_half(512, vB, tagt, pendB);
      if (pendB) __builtin_amdgcn_s_sleep(1);
    }
    __syncthreads();

    // ---- h part B: kk 16..31 ----
    {
      const _Float16* hl = &Hlds[n * HPITCH + q * 8];
#pragma unroll
      for (int kk = NHMF / 2; kk < NHMF; kk += 4) {
        f16x8 f0 = *(const f16x8*)(hl + kk * 32);
        f16x8 f1 = *(const f16x8*)(hl + (kk + 1) * 32);
        f16x8 f2 = *(const f16x8*)(hl + (kk + 2) * 32);
        f16x8 f3 = *(const f16x8*)(hl + (kk + 3) * 32);
        a0 = __builtin_amdgcn_mfma_f32_16x16x32_f16(f0, Bfrag[NXMF + kk], a0,
                                                    0, 0, 0);
        a1 = __builtin_amdgcn_mfma_f32_16x16x32_f16(f1, Bfrag[NXMF + kk + 1],
                                                    a1, 0, 0, 0);
        a2 = __builtin_amdgcn_mfma_f32_16x16x32_f16(f2, Bfrag[NXMF + kk + 2],
                                                    a2, 0, 0, 0);
        a3 = __builtin_amdgcn_mfma_f32_16x16x32_f16(f3, Bfrag[NXMF + kk + 3],
                                                    a3, 0, 0, 0);
      }
    }
    const f32x4 acc = (a0 + a1) + (a2 + a3);

    // ---- epilogue: nonlinearities (all lanes, uniform code) ----
    float v[4];
#pragma unroll
    for (int r = 0; r < 4; ++r) {
      const float z = acc[r];
      v[r] = (gate == 2) ? fast_tanh(z) : fast_sigmoid(z);
    }
    float vi[4], vg[4], vo[4];
#pragma unroll
    for (int r = 0; r < 4; ++r) {
      vi[r] = __shfl(v[r], (lane + 4) & 63, 64);
      vg[r] = __shfl(v[r], (lane + 8) & 63, 64);
      vo[r] = __shfl(v[r], (lane + 12) & 63, 64);
    }
    float hv[4];
#pragma unroll
    for (int r = 0; r < 4; ++r) {
      const float c = fmaf(v[r], c_reg[r], vi[r] * vg[r]);
      c_reg[r] = c;
      hv[r] = vo[r] * fast_tanh(c);
    }
    // gather the 4 contiguous columns (j0w..j0w+3) onto lane n==0
    float h1[4], h2[4], h3[4];
#pragma unroll
    for (int r = 0; r < 4; ++r) {
      h1[r] = __shfl(hv[r], (lane + 1) & 63, 64);
      h2[r] = __shfl(hv[r], (lane + 2) & 63, 64);
      h3[r] = __shfl(hv[r], (lane + 3) & 63, 64);
    }
    // tagged h-stores: u32 = (fp16<<16)|tag, two 8B agent stores per row.
    if (n == 0) {
      const unsigned tag = (unsigned)(t + 1) & 0xFFFFu;
      unsigned* hn = hbuf + (size_t)((t + 1) & 1) * B * H;
#pragma unroll
      for (int r = 0; r < 4; ++r) {
        const int b = brow0 + q * 4 + r;
        union {
          _Float16 f;
          unsigned short s;
        } c0, c1, c2, c3;
        c0.f = (_Float16)hv[r];
        c1.f = (_Float16)h1[r];
        c2.f = (_Float16)h2[r];
        c3.f = (_Float16)h3[r];
        const unsigned w0 = ((unsigned)c0.s << 16) | tag;
        const unsigned w1 = ((unsigned)c1.s << 16) | tag;
        const unsigned w2 = ((unsigned)c2.s << 16) | tag;
        const unsigned w3 = ((unsigned)c3.s << 16) | tag;
        unsigned long long* p =
            (unsigned long long*)(hn + (size_t)b * H + j0w);
        store_sc1_u64p(p, (unsigned long long)w0 |
                              ((unsigned long long)w1 << 32));
        store_sc1_u64p(p + 1, (unsigned long long)w2 |
                                  ((unsigned long long)w3 << 32));
      }
    }

    // ---- fallback: stage x[t+1] rows of OWN group into next buffer ----
    if (!PRE && t + 1 < T_STEPS && tid < 16) {
      _Float16* xn = xbuf + (size_t)((t + 1) & 1) * B * IN;
      const int row = brow0 + (jgrp >> 2);         // 4 blocks per row
      const int off = (jgrp & 3) * 128 + tid * 8;  // quarter of 512
      const float* xs = x + (size_t)(t + 1) * B * IN + (size_t)row * IN + off;
      const float4 x0 = *(const float4*)xs;
      const float4 x1 = *(const float4*)(xs + 4);
      float vals[8] = {x0.x, x0.y, x0.z, x0.w, x1.x, x1.y, x1.z, x1.w};
#pragma unroll
      for (int i = 0; i < 4; ++i) {
        union {
          _Float16 h[2];
          unsigned u;
        } pk;
        pk.h[0] = (_Float16)vals[2 * i];
        pk.h[1] = (_Float16)vals[2 * i + 1];
        store_sc1_u32((unsigned*)(xn + (size_t)row * IN + off + 2 * i), pk.u);
      }
    }

    if (t + 1 < T_STEPS) {
      if (PRE) {
        // raw barrier: all waves' tagged stores are ISSUED; no vmcnt drain.
        // Tags make the flag purely advisory.
        asm volatile("" ::: "memory");
        __builtin_amdgcn_s_barrier();
        asm volatile("" ::: "memory");
      } else {
        __syncthreads();  // fallback keeps the full drain (x + h visible)
      }
      if (tid == 0) store_sc1_u32(flags + jgrp, (unsigned)(t + 1));
      // out-stores + next-step x GEMM hide under barrier propagation
      if (n == 0) {
#pragma unroll
        for (int r = 0; r < 4; ++r) {
          const int b = brow0 + q * 4 + r;
          const float4 o4 = make_float4(hv[r], h1[r], h2[r], h3[r]);
          *(float4*)(out + (size_t)t * B * H + (size_t)b * H + j0w) = o4;
        }
      }
      if (PRE) xpart(t + 1);
      // speculative A first pass for t+1: fresh granules land in LDS while
      // we wait; stale ones retried at next loop top. (Hlds A-region is
      // safe: all waves passed the raw barrier, so MFMA(t) reads are done.)
      {
        const unsigned* hn32 =
            hbuf + (size_t)((t + 1) & 1) * B * H + (size_t)brow0 * H;
        pendA = 0xFFu;
        issue_half(hn32, 0, vA, pendA);
        check_half(0, vA, (unsigned)(t + 1) & 0xFFFFu, pendA);
      }
      // wave 0 scans the group's 64 flags (one u32 per lane, 4 lines);
      // waves 1-3 wait at a raw barrier (no vmcnt drain).
      if (wv == 0) {
        const unsigned tgt = (unsigned)(t + 1);
        for (;;) {
          const unsigned f = __hip_atomic_load(flags + lane, __ATOMIC_RELAXED,
                                               __HIP_MEMORY_SCOPE_AGENT);
          if (__all(f >= tgt)) break;
          __builtin_amdgcn_s_sleep(1);
        }
      }
      asm volatile("" ::: "memory");
      __builtin_amdgcn_s_barrier();
      asm volatile("" ::: "memory");
      if (!PRE) xpart(t + 1);  // xbuf sc1 loads are safe only post-poll
    } else {
      // final step: out row + hx + cx (no barrier needed)
      float c1[4], c2[4], c3[4];
#pragma unroll
      for (int r = 0; r < 4; ++r) {
        c1[r] = __shfl(c_reg[r], (lane + 1) & 63, 64);
        c2[r] = __shfl(c_reg[r], (lane + 2) & 63, 64);
        c3[r] = __shfl(c_reg[r], (lane + 3) & 63, 64);
      }
      if (n == 0) {
#pragma unroll
        for (int r = 0; r < 4; ++r) {
          const int b = brow0 + q * 4 + r;
          const float4 o4 = make_float4(hv[r], h1[r], h2[r], h3[r]);
          *(float4*)(out + (size_t)t * B * H + (size_t)b * H + j0w) = o4;
          *(float4*)(out + (size_t)T_STEPS * B * H + (size_t)b * H + j0w) =
              o4;  // hx
          const float4 c4 = make_float4(c_reg[r], c1[r], c2[r], c3[r]);
          *(float4*)(out + (size_t)T_STEPS * B * H + (size_t)B * H +
                     (size_t)b * H + j0w) = c4;  // cx
        }
      }
    }
  }
}

}  // namespace

extern "C" void kernel_launch(void* const* d_in, const int* in_sizes, int n_in,
                              void* d_out, int out_size, void* d_ws,
                              size_t ws_size, hipStream_t stream) {
  const float* x = (const float*)d_in[0];
  const float* Wf = (const float*)d_in[1];
  const float* bf = (const float*)d_in[2];
  const float* Wi = (const float*)d_in[3];
  const float* bi = (const float*)d_in[4];
  const float* Wg = (const float*)d_in[5];
  const float* bg = (const float*)d_in[6];
  const float* Wo = (const float*)d_in[7];
  const float* bo = (const float*)d_in[8];
  float* out = (float*)d_out;

  char* ws = (char*)d_ws;
  unsigned* hbuf = (unsigned*)(ws + HBUF_OFF);
  _Float16* xbuf = (_Float16*)(ws + XBUF_OFF);
  unsigned* bar = (unsigned*)(ws + BAR_OFF);
  _Float16* combx = (_Float16*)(ws + COMBX_OFF);

  const bool pre = ws_size >= NEED_PRE;

  if (pre) {
    const size_t n = (size_t)T_STEPS * B * IN;
    prep_pre<<<(unsigned)((n + 255) / 256), 256, 0, stream>>>(x, combx, hbuf,
                                                              bar);
    lstm_persist<true><<<NBLK, 256, 0, stream>>>(
        x, Wf, Wi, Wg, Wo, bf, bi, bg, bo, out, combx, xbuf, hbuf, bar);
  } else {
    prep_fb<<<(2 * B * H + 255) / 256, 256, 0, stream>>>(x, xbuf, hbuf, bar);
    lstm_persist<false><<<NBLK, 256, 0, stream>>>(
        x, Wf, Wi, Wg, Wo, bf, bi, bg, bo, out, combx, xbuf, hbuf, bar);
  }
}